// Round 8
// baseline (231.624 us; speedup 1.0000x reference)
//
#include <hip/hip_runtime.h>

#define PBIN 14
#define SSAMP 2
#define SCALE_F 0.0625f
#define TRANS_STD 0.1f
#define CCH 256
#define FCDIM 1024
#define NROIS 192
#define HH 128
#define WW 128
#define PP (PBIN*PBIN)      // 196
#define KDIM (CCH*PP)       // 50176

typedef __bf16 bf16x8 __attribute__((ext_vector_type(8)));
typedef float  f32x4  __attribute__((ext_vector_type(4)));
typedef unsigned u32x4 __attribute__((ext_vector_type(4)));
typedef unsigned u32x2 __attribute__((ext_vector_type(2)));

__device__ __forceinline__ unsigned short f2bf(float f) {
  unsigned u = __builtin_bit_cast(unsigned, f);
  u += 0x7FFFu + ((u >> 16) & 1u);   // RNE
  return (unsigned short)(u >> 16);
}
__device__ __forceinline__ unsigned pk2(float lo, float hi) {
  unsigned ulo = __builtin_bit_cast(unsigned, lo) + 0x8000u;
  unsigned uhi = __builtin_bit_cast(unsigned, hi) + 0x8000u;
  return __builtin_amdgcn_perm(uhi, ulo, 0x07060302u);
}
__device__ __forceinline__ float bf_lo(unsigned u) {
  return __builtin_bit_cast(float, u << 16);
}
__device__ __forceinline__ float bf_hi(unsigned u) {
  return __builtin_bit_cast(float, u & 0xFFFF0000u);
}
__device__ __forceinline__ float bf_u16(unsigned short v) {
  return __builtin_bit_cast(float, (unsigned)v << 16);
}

// -------- transpose+convert x [B,C,H,W] f32 -> xt [B,H,W,C/2] u32(bf16 pair) --
__global__ __launch_bounds__(256) void transpose_x_kernel(
    const float* __restrict__ x, unsigned* __restrict__ xt)
{
  __shared__ float tile[32][33];
  int tx = threadIdx.x, ty = threadIdx.y;     // (32, 8)
  int hw0 = blockIdx.x * 32;
  int c0  = blockIdx.y * 32;
  int b   = blockIdx.z;
  const float* xb = x + (size_t)b * CCH * HH * WW;
  unsigned* xtb   = xt + (size_t)b * (HH*WW) * (CCH/2);
#pragma unroll
  for (int k = 0; k < 4; ++k)
    tile[ty + k*8][tx] = xb[(size_t)(c0 + ty + k*8) * (HH*WW) + hw0 + tx];
  __syncthreads();
  int l  = ty*32 + tx;
  int cp = l & 15;
  int hr = l >> 4;
#pragma unroll
  for (int k = 0; k < 2; ++k) {
    int row = hr + k*16;
    unsigned pkd = pk2(tile[2*cp][row], tile[2*cp+1][row]);
    xtb[(size_t)(hw0 + row) * (CCH/2) + (c0>>1) + cp] = pkd;
  }
}

// ---------------- PSRoI pool: wave = bin; lane = (tap-half, channel-oct) ------
// Each lane loads u32x4 (8 ch) for taps q+8h, halves combined via shfl_xor(32).
// MODE 0: base -> bf16 [n][p*256+c]. MODE 1: read om, *sigmoid(mask) -> f32.
template<int MODE>
__global__ __launch_bounds__(256) void pool_kernel(
    const unsigned* __restrict__ xt, const float* __restrict__ rois,
    const float* __restrict__ om, void* __restrict__ outp)
{
  __shared__ float lds[4][256];
  const int t = threadIdx.x;
  const int wv = t >> 6, lane = t & 63;
  const int n  = blockIdx.x;
  const int p0 = blockIdx.y * 4;
  const int p  = p0 + wv;
  const int ph = p / PBIN, pw = p % PBIN;

  float rb = rois[n*5 + 0];
  float x1 = rois[n*5 + 1], y1 = rois[n*5 + 2];
  float x2 = rois[n*5 + 3], y2 = rois[n*5 + 4];
  int b = (int)rb;
  float sw = rintf(x1) * SCALE_F - 0.5f;
  float sh = rintf(y1) * SCALE_F - 0.5f;
  float ew = (rintf(x2) + 1.0f) * SCALE_F - 0.5f;
  float eh = (rintf(y2) + 1.0f) * SCALE_F - 0.5f;
  float rw = fmaxf(ew - sw, 0.1f);
  float rh = fmaxf(eh - sh, 0.1f);
  float bw = rw / PBIN, bh = rh / PBIN;
  float subw = bw / SSAMP, subh = bh / SSAMP;

  float tx = 0.f, ty = 0.f, mval = 1.f;
  if (MODE == 1) {
    const float* omr = om + (size_t)n * (3*PP);
    tx = omr[p] * TRANS_STD;
    ty = omr[PP + p] * TRANS_STD;
    mval = 1.0f / (1.0f + expf(-omr[2*PP + p]));
  }
  float wstart = pw * bw + sw + tx * rw;
  float hstart = ph * bh + sh + ty * rh;

  int offs[16];
  float wts[16];
  float cnt = 0.f;
  int base_b = b * (HH*WW);
#pragma unroll
  for (int ih = 0; ih < SSAMP; ++ih) {
#pragma unroll
    for (int iw = 0; iw < SSAMP; ++iw) {
      float wv_ = wstart + iw * subw;
      float hv_ = hstart + ih * subh;
      float validf = (wv_ >= -0.5f && wv_ <= WW - 0.5f &&
                      hv_ >= -0.5f && hv_ <= HH - 0.5f) ? 1.f : 0.f;
      cnt += validf;
      float wc = fminf(fmaxf(wv_, 0.f), WW - 1.0f);
      float hc = fminf(fmaxf(hv_, 0.f), HH - 1.0f);
      int x0 = (int)floorf(wc), y0 = (int)floorf(hc);
      int x1i = min(x0 + 1, WW - 1), y1i = min(y0 + 1, HH - 1);
      float lx = wc - (float)x0, ly = hc - (float)y0;
      int s4 = (ih*2 + iw) * 4;
      offs[s4+0] = (base_b + y0 *WW + x0 ) * (CCH/2);
      offs[s4+1] = (base_b + y0 *WW + x1i) * (CCH/2);
      offs[s4+2] = (base_b + y1i*WW + x0 ) * (CCH/2);
      offs[s4+3] = (base_b + y1i*WW + x1i) * (CCH/2);
      wts[s4+0] = validf * (1.f-ly)*(1.f-lx);
      wts[s4+1] = validf * (1.f-ly)*lx;
      wts[s4+2] = validf * ly*(1.f-lx);
      wts[s4+3] = validf * ly*lx;
    }
  }
  float inv = 1.0f / fmaxf(cnt, 1.0f);
  if (MODE == 1) inv *= mval;

  const int h = lane >> 5;        // tap half
  const int j = lane & 31;        // channel-oct (8 ch)
  f32x4 a0 = {0.f,0.f,0.f,0.f}, a1 = {0.f,0.f,0.f,0.f};
#pragma unroll
  for (int q = 0; q < 8; ++q) {
    int   off = h ? offs[q+8] : offs[q];     // compile-time array indices
    float w   = h ? wts[q+8]  : wts[q];
    u32x4 v = *(const u32x4*)&xt[off + 4*j];
    a0[0] += w * bf_lo(v[0]); a0[1] += w * bf_hi(v[0]);
    a0[2] += w * bf_lo(v[1]); a0[3] += w * bf_hi(v[1]);
    a1[0] += w * bf_lo(v[2]); a1[1] += w * bf_hi(v[2]);
    a1[2] += w * bf_lo(v[3]); a1[3] += w * bf_hi(v[3]);
  }
#pragma unroll
  for (int e = 0; e < 4; ++e) {
    a0[e] += __shfl_xor(a0[e], 32, 64);
    a1[e] += __shfl_xor(a1[e], 32, 64);
  }
  f32x4 av = h ? a1 : a0;
  av *= inv;
  const int ch = 8*j + 4*h;       // this lane writes channels ch..ch+3

  if (MODE == 0) {
    unsigned short* bout = (unsigned short*)outp;
    u32x2 pkd = { pk2(av[0], av[1]), pk2(av[2], av[3]) };
    *(u32x2*)&bout[(size_t)n*KDIM + p*CCH + ch] = pkd;
  } else {
    *(f32x4*)&lds[wv][ch] = av;
    __syncthreads();
    float* fout = (float*)outp;
    int c = t;
    f32x4 o = { lds[0][c], lds[1][c], lds[2][c], lds[3][c] };
    *(f32x4*)&fout[(size_t)n*KDIM + (size_t)c*PP + p0] = o;
  }
}

// ---------------- split-K GEMM: partial[s] (bf16) = A(bf16 192xK) * bf16(B) ---
// BM=192, BN=128, BK=32, 8 waves as 4m x 2n (wave tile 48x64). 1D grid NB*S.
// B loaded as 2x f32x4 per thread (512B wave transactions), pk2 at staging.
// SWZ=1 (NB==8, S%8==0): same-split n-blocks share one XCD's L2 for A.
template<int PERM, int SWZ>
__global__ __launch_bounds__(512, 4) void gemm_splitk(
    const unsigned* __restrict__ A, int ldAu,
    const float* __restrict__ Bm, int N, int ldB,
    unsigned short* __restrict__ partial, int NB, int S, int chunks)
{
  __shared__ __align__(16) unsigned lds_a[192*20];   // [m][16 u32 + pad4]
  __shared__ __align__(16) unsigned lds_b[128*18];   // [n][16 u32(k-pairs) + pad2]

  int t   = threadIdx.x;
  int bid = blockIdx.x;
  int s, nblk;
  if (SWZ) {            // NB==8, S%8==0, grid%64==0
    int xcd = bid & 7;
    nblk    = (bid >> 3) & 7;
    s       = xcd * (S >> 3) + (bid >> 6);
  } else {
    nblk = bid % NB;
    s    = bid / NB;
  }
  int n0 = nblk * 128;
  int q = chunks / S, r = chunks % S;
  int myc = q + (s < r ? 1 : 0);
  int c0 = s*q + (s < r ? s : r);
  int k0 = c0 * 32;

  int wv = t >> 6, lane = t & 63;
  int wm = wv & 3, wn = wv >> 2;               // 4m x 2n
  int m0w = wm * 48;
  int n0w = wn * 64;
  int lrow = lane & 15, lg = lane >> 4;

  f32x4 acc[3][4];
#pragma unroll
  for (int i = 0; i < 3; ++i)
#pragma unroll
    for (int j = 0; j < 4; ++j) acc[i][j] = {0.f,0.f,0.f,0.f};

  u32x2 areg[3];
  f32x4 bva, bvb;
  const int am  = t >> 3;         // 0..63 (A row within 64-row pass)
  const int akp = (t & 7) * 2;    // u32-pair within 16-u32 row chunk
  const int nq  = t & 31;         // B: n-quad (n = 4*nq)
  const int ku  = t >> 5;         // B: k-pair 0..15 (k = 2*ku)

  auto load_tile = [&](int it) {
    int kg = k0 + it*32;
#pragma unroll
    for (int i = 0; i < 3; ++i) {
      int m = am + i*64;
      areg[i] = *(const u32x2*)&A[(size_t)m*ldAu + (kg>>1) + akp];
    }
    int ka = kg + 2*ku, kb = ka + 1;
    size_t sra = PERM ? ((size_t)(ka & 255)*PP + (ka >> 8)) : (size_t)ka;
    size_t srb = PERM ? ((size_t)(kb & 255)*PP + (kb >> 8)) : (size_t)kb;
    int gn = n0 + nq*4;
    if (gn + 3 < N) {
      bva = *(const f32x4*)&Bm[sra*ldB + gn];
      bvb = *(const f32x4*)&Bm[srb*ldB + gn];
    } else {
#pragma unroll
      for (int e = 0; e < 4; ++e) {
        bva[e] = (gn + e < N) ? Bm[sra*ldB + gn + e] : 0.f;
        bvb[e] = (gn + e < N) ? Bm[srb*ldB + gn + e] : 0.f;
      }
    }
  };

  load_tile(0);
  for (int it = 0; it < myc; ++it) {
    __syncthreads();
#pragma unroll
    for (int i = 0; i < 3; ++i) {
      int m = am + i*64;
      *(u32x2*)&lds_a[m*20 + akp] = areg[i];
    }
#pragma unroll
    for (int jj = 0; jj < 4; ++jj)
      lds_b[(nq*4 + jj)*18 + ku] = pk2(bva[jj], bvb[jj]);
    __syncthreads();
    if (it + 1 < myc) load_tile(it + 1);      // overlap HBM with compute

    bf16x8 af[3];
#pragma unroll
    for (int mf = 0; mf < 3; ++mf) {
      u32x4 ra = *(const u32x4*)&lds_a[(m0w + mf*16 + lrow)*20 + lg*4];
      af[mf] = __builtin_bit_cast(bf16x8, ra);
    }
    bf16x8 bfrag[4];
#pragma unroll
    for (int nf = 0; nf < 4; ++nf) {
      int col = n0w + nf*16 + lrow;
      u32x2 r0 = *(const u32x2*)&lds_b[col*18 + lg*4];
      u32x2 r1 = *(const u32x2*)&lds_b[col*18 + lg*4 + 2];
      u32x4 ub = { r0[0], r0[1], r1[0], r1[1] };
      bfrag[nf] = __builtin_bit_cast(bf16x8, ub);
    }
#pragma unroll
    for (int nf = 0; nf < 4; ++nf)
#pragma unroll
      for (int mf = 0; mf < 3; ++mf)
        acc[mf][nf] = __builtin_amdgcn_mfma_f32_16x16x32_bf16(af[mf], bfrag[nf], acc[mf][nf], 0, 0, 0);
  }

#pragma unroll
  for (int mf = 0; mf < 3; ++mf) {
#pragma unroll
    for (int nf = 0; nf < 4; ++nf) {
      int gcol = n0 + n0w + nf*16 + lrow;
      if (gcol < N) {
#pragma unroll
        for (int rr = 0; rr < 4; ++rr) {
          int m = m0w + mf*16 + lg*4 + rr;
          partial[((size_t)s*NROIS + m)*N + gcol] = f2bf(acc[mf][nf][rr]);
        }
      }
    }
  }
}

// ------- reduce bf16 partials + bias + relu -> bf16 f (4 vals/thread) ---------
__global__ __launch_bounds__(256) void reduce_kernel(
    const unsigned short* __restrict__ partial, const float* __restrict__ bias,
    unsigned short* __restrict__ outp, int N, int S)
{
  int nn = (blockIdx.x*256 + threadIdx.x) * 4;
  int m  = blockIdx.y;
  if (nn >= N) return;
  f32x4 a = *(const f32x4*)&bias[nn];
  size_t stride = (size_t)NROIS * N;
  const unsigned short* p = &partial[(size_t)m*N + nn];
#pragma unroll 4
  for (int s = 0; s < S; ++s) {
    u32x2 v = *(const u32x2*)&p[(size_t)s*stride];
    a[0] += bf_lo(v[0]); a[1] += bf_hi(v[0]);
    a[2] += bf_lo(v[1]); a[3] += bf_hi(v[1]);
  }
  a[0] = fmaxf(a[0], 0.f); a[1] = fmaxf(a[1], 0.f);
  a[2] = fmaxf(a[2], 0.f); a[3] = fmaxf(a[3], 0.f);
  u32x2 pkd = { pk2(a[0], a[1]), pk2(a[2], a[3]) };
  *(u32x2*)&outp[(size_t)m*N + nn] = pkd;
}

// ------- reduce3: om[n][d] = b3[d] + sum_s p3[s][n][d]  (f32 out, 588 wide) ---
__global__ __launch_bounds__(640) void reduce3_kernel(
    const unsigned short* __restrict__ p3, const float* __restrict__ b3,
    float* __restrict__ om, int S)
{
  int d = threadIdx.x;
  int nn = blockIdx.x;
  if (d >= 3*PP) return;
  float a = b3[d];
#pragma unroll 4
  for (int s = 0; s < S; ++s)
    a += bf_u16(p3[((size_t)s*NROIS + nn)*(3*PP) + d]);
  om[(size_t)nn*(3*PP) + d] = a;
}

extern "C" void kernel_launch(void* const* d_in, const int* in_sizes, int n_in,
                              void* d_out, int out_size, void* d_ws, size_t ws_size,
                              hipStream_t stream)
{
  const float* x    = (const float*)d_in[0];
  const float* rois = (const float*)d_in[1];
  const float* w1   = (const float*)d_in[2];
  const float* b1   = (const float*)d_in[3];
  const float* w2   = (const float*)d_in[4];
  const float* b2   = (const float*)d_in[5];
  const float* w3   = (const float*)d_in[6];
  const float* b3   = (const float*)d_in[7];

  char* ws = (char*)d_ws;
  size_t off = 0;
  unsigned* xt = (unsigned*)(ws + off);               off += (size_t)2*(HH*WW)*(CCH/2)*4;
  unsigned short* base = (unsigned short*)(ws + off); off += (size_t)NROIS*KDIM*2;
  unsigned short* f1 = (unsigned short*)(ws + off);   off += (size_t)NROIS*FCDIM*2;
  unsigned short* f2 = (unsigned short*)(ws + off);   off += (size_t)NROIS*FCDIM*2;
  float* om = (float*)(ws + off);                     off += (size_t)NROIS*(3*PP)*4;
  const int S1 = 64, S2 = 32, S3 = 16;
  unsigned short* partial1 = (unsigned short*)(ws + off); off += (size_t)S1*NROIS*FCDIM*2;  // 25.2MB
  unsigned short* partial2 = (unsigned short*)(ws + off); off += (size_t)S2*NROIS*FCDIM*2;  // 12.6MB
  unsigned short* partial3 = (unsigned short*)(ws + off); off += (size_t)S3*NROIS*(3*PP)*2; // 3.6MB
  (void)ws_size;

  // 1) transpose+bf16 x -> xt
  transpose_x_kernel<<<dim3(512, 8, 2), dim3(32, 8), 0, stream>>>(x, xt);
  // 2) base pool -> bf16 [192, 50176] (k = p*256+c)
  pool_kernel<0><<<dim3(NROIS, PP/4), 256, 0, stream>>>(xt, rois, nullptr, base);
  // 3) f1 = relu(base @ w1 + b1); 1568 K-chunks, 64 splits, XCD-swizzled
  gemm_splitk<1,1><<<8*S1, 512, 0, stream>>>((const unsigned*)base, KDIM/2, w1, FCDIM, FCDIM, partial1, 8, S1, KDIM/32);
  reduce_kernel<<<dim3(1, NROIS), 256, 0, stream>>>(partial1, b1, f1, FCDIM, S1);
  // 4) f2 = relu(f1 @ w2 + b2)
  gemm_splitk<0,1><<<8*S2, 512, 0, stream>>>((const unsigned*)f1, FCDIM/2, w2, FCDIM, FCDIM, partial2, 8, S2, FCDIM/32);
  reduce_kernel<<<dim3(1, NROIS), 256, 0, stream>>>(partial2, b2, f2, FCDIM, S2);
  // 5) partial3 = split-K of f2 @ w3 (N = 588)
  gemm_splitk<0,0><<<5*S3, 512, 0, stream>>>((const unsigned*)f2, FCDIM/2, w3, 3*PP, 3*PP, partial3, 5, S3, FCDIM/32);
  // 5b) om = b3 + sum partial3 (f32)
  reduce3_kernel<<<NROIS, 640, 0, stream>>>(partial3, b3, om, S3);
  // 6) final pool reads om, * sigmoid(mask) -> d_out
  pool_kernel<1><<<dim3(NROIS, PP/4), 256, 0, stream>>>(xt, rois, om, d_out);
}

// Round 9
// 162.369 us; speedup vs baseline: 1.4265x; 1.4265x over previous
//
#include <hip/hip_runtime.h>

#define PBIN 14
#define SSAMP 2
#define SCALE_F 0.0625f
#define TRANS_STD 0.1f
#define CCH 256
#define FCDIM 1024
#define NROIS 192
#define HH 128
#define WW 128
#define PP (PBIN*PBIN)      // 196
#define KDIM (CCH*PP)       // 50176

typedef __bf16 bf16x8 __attribute__((ext_vector_type(8)));
typedef float  f32x4  __attribute__((ext_vector_type(4)));
typedef unsigned u32x4 __attribute__((ext_vector_type(4)));
typedef unsigned u32x2 __attribute__((ext_vector_type(2)));

__device__ __forceinline__ unsigned short f2bf(float f) {
  unsigned u = __builtin_bit_cast(unsigned, f);
  u += 0x7FFFu + ((u >> 16) & 1u);   // RNE
  return (unsigned short)(u >> 16);
}
__device__ __forceinline__ unsigned pk2(float lo, float hi) {
  unsigned ulo = __builtin_bit_cast(unsigned, lo) + 0x8000u;
  unsigned uhi = __builtin_bit_cast(unsigned, hi) + 0x8000u;
  return __builtin_amdgcn_perm(uhi, ulo, 0x07060302u);
}
__device__ __forceinline__ float bf_lo(unsigned u) {
  return __builtin_bit_cast(float, u << 16);
}
__device__ __forceinline__ float bf_hi(unsigned u) {
  return __builtin_bit_cast(float, u & 0xFFFF0000u);
}
__device__ __forceinline__ float bf_u16(unsigned short v) {
  return __builtin_bit_cast(float, (unsigned)v << 16);
}

// -------- transpose+convert x [B,C,H,W] f32 -> xt [B,H,W,C/2] u32(bf16 pair) --
__global__ __launch_bounds__(256) void transpose_x_kernel(
    const float* __restrict__ x, unsigned* __restrict__ xt)
{
  __shared__ float tile[32][33];
  int tx = threadIdx.x, ty = threadIdx.y;     // (32, 8)
  int hw0 = blockIdx.x * 32;
  int c0  = blockIdx.y * 32;
  int b   = blockIdx.z;
  const float* xb = x + (size_t)b * CCH * HH * WW;
  unsigned* xtb   = xt + (size_t)b * (HH*WW) * (CCH/2);
#pragma unroll
  for (int k = 0; k < 4; ++k)
    tile[ty + k*8][tx] = xb[(size_t)(c0 + ty + k*8) * (HH*WW) + hw0 + tx];
  __syncthreads();
  int l  = ty*32 + tx;
  int cp = l & 15;
  int hr = l >> 4;
#pragma unroll
  for (int k = 0; k < 2; ++k) {
    int row = hr + k*16;
    unsigned pkd = pk2(tile[2*cp][row], tile[2*cp+1][row]);
    xtb[(size_t)(hw0 + row) * (CCH/2) + (c0>>1) + cp] = pkd;
  }
}

// ---------------- PSRoI pool: wave = bin, lane = channel-quad -----------------
// MODE 0: base -> bf16 [n][p*256+c]. MODE 1: read om (f32), *sigmoid(mask) -> f32.
template<int MODE>
__global__ __launch_bounds__(256) void pool_kernel(
    const unsigned* __restrict__ xt, const float* __restrict__ rois,
    const float* __restrict__ om, void* __restrict__ outp)
{
  __shared__ float lds[4][256];
  const int t = threadIdx.x;
  const int wv = t >> 6, lane = t & 63;
  const int n  = blockIdx.x;
  const int p0 = blockIdx.y * 4;
  const int p  = p0 + wv;
  const int ph = p / PBIN, pw = p % PBIN;

  float rb = rois[n*5 + 0];
  float x1 = rois[n*5 + 1], y1 = rois[n*5 + 2];
  float x2 = rois[n*5 + 3], y2 = rois[n*5 + 4];
  int b = (int)rb;
  float sw = rintf(x1) * SCALE_F - 0.5f;
  float sh = rintf(y1) * SCALE_F - 0.5f;
  float ew = (rintf(x2) + 1.0f) * SCALE_F - 0.5f;
  float eh = (rintf(y2) + 1.0f) * SCALE_F - 0.5f;
  float rw = fmaxf(ew - sw, 0.1f);
  float rh = fmaxf(eh - sh, 0.1f);
  float bw = rw / PBIN, bh = rh / PBIN;
  float subw = bw / SSAMP, subh = bh / SSAMP;

  float tx = 0.f, ty = 0.f, mval = 1.f;
  if (MODE == 1) {
    const float* omr = om + (size_t)n * (3*PP);
    tx = omr[p] * TRANS_STD;
    ty = omr[PP + p] * TRANS_STD;
    mval = 1.0f / (1.0f + expf(-omr[2*PP + p]));
  }
  float wstart = pw * bw + sw + tx * rw;
  float hstart = ph * bh + sh + ty * rh;

  int offs[16];
  float wts[16];
  float cnt = 0.f;
  int base_b = b * (HH*WW);
#pragma unroll
  for (int ih = 0; ih < SSAMP; ++ih) {
#pragma unroll
    for (int iw = 0; iw < SSAMP; ++iw) {
      float wv_ = wstart + iw * subw;
      float hv_ = hstart + ih * subh;
      float validf = (wv_ >= -0.5f && wv_ <= WW - 0.5f &&
                      hv_ >= -0.5f && hv_ <= HH - 0.5f) ? 1.f : 0.f;
      cnt += validf;
      float wc = fminf(fmaxf(wv_, 0.f), WW - 1.0f);
      float hc = fminf(fmaxf(hv_, 0.f), HH - 1.0f);
      int x0 = (int)floorf(wc), y0 = (int)floorf(hc);
      int x1i = min(x0 + 1, WW - 1), y1i = min(y0 + 1, HH - 1);
      float lx = wc - (float)x0, ly = hc - (float)y0;
      int s4 = (ih*2 + iw) * 4;
      offs[s4+0] = (base_b + y0 *WW + x0 ) * (CCH/2);
      offs[s4+1] = (base_b + y0 *WW + x1i) * (CCH/2);
      offs[s4+2] = (base_b + y1i*WW + x0 ) * (CCH/2);
      offs[s4+3] = (base_b + y1i*WW + x1i) * (CCH/2);
      wts[s4+0] = validf * (1.f-ly)*(1.f-lx);
      wts[s4+1] = validf * (1.f-ly)*lx;
      wts[s4+2] = validf * ly*(1.f-lx);
      wts[s4+3] = validf * ly*lx;
    }
  }
  float inv = 1.0f / fmaxf(cnt, 1.0f);
  if (MODE == 1) inv *= mval;

  const int cl = lane * 4;
  f32x4 acc = {0.f, 0.f, 0.f, 0.f};
#pragma unroll
  for (int s = 0; s < 16; ++s) {
    u32x2 v = *(const u32x2*)&xt[offs[s] + lane*2];
    acc[0] += wts[s] * bf_lo(v[0]);
    acc[1] += wts[s] * bf_hi(v[0]);
    acc[2] += wts[s] * bf_lo(v[1]);
    acc[3] += wts[s] * bf_hi(v[1]);
  }
  acc *= inv;

  if (MODE == 0) {
    unsigned short* bout = (unsigned short*)outp;
    u32x2 pkd = { pk2(acc[0], acc[1]), pk2(acc[2], acc[3]) };
    *(u32x2*)&bout[(size_t)n*KDIM + p*CCH + cl] = pkd;
  } else {
    *(f32x4*)&lds[wv][cl] = acc;
    __syncthreads();
    float* fout = (float*)outp;
    int c = t;
    f32x4 o = { lds[0][c], lds[1][c], lds[2][c], lds[3][c] };
    *(f32x4*)&fout[(size_t)n*KDIM + (size_t)c*PP + p0] = o;
  }
}

// ---------------- split-K GEMM: partial[s] (bf16) = A(bf16 192xK) * bf16(B) ---
// BM=192, BN=128, BK=32, 8 waves as 4m x 2n (wave tile 48x64). 1D grid NB*S.
// B staged as packed bf16-pair u32 [n][16+2pad]; conversion at staging.
// SWZ=1 (NB==8, S%8==0): same-split n-blocks share one XCD's L2 for A.
template<int PERM, int SWZ>
__global__ __launch_bounds__(512, 4) void gemm_splitk(
    const unsigned* __restrict__ A, int ldAu,
    const float* __restrict__ Bm, int N, int ldB,
    unsigned short* __restrict__ partial, int NB, int S, int chunks)
{
  __shared__ __align__(16) unsigned lds_a[192*20];   // [m][16 u32 + pad4]
  __shared__ __align__(16) unsigned lds_b[128*18];   // [n][16 u32(k-pairs) + pad2]

  int t   = threadIdx.x;
  int bid = blockIdx.x;
  int s, nblk;
  if (SWZ) {            // NB==8, S%8==0, grid%64==0
    int xcd = bid & 7;
    nblk    = (bid >> 3) & 7;
    s       = xcd * (S >> 3) + (bid >> 6);
  } else {
    nblk = bid % NB;
    s    = bid / NB;
  }
  int n0 = nblk * 128;
  int q = chunks / S, r = chunks % S;
  int myc = q + (s < r ? 1 : 0);
  int c0 = s*q + (s < r ? s : r);
  int k0 = c0 * 32;

  int wv = t >> 6, lane = t & 63;
  int wm = wv & 3, wn = wv >> 2;               // 4m x 2n
  int m0w = wm * 48;
  int n0w = wn * 64;
  int lrow = lane & 15, lg = lane >> 4;

  f32x4 acc[3][4];
#pragma unroll
  for (int i = 0; i < 3; ++i)
#pragma unroll
    for (int j = 0; j < 4; ++j) acc[i][j] = {0.f,0.f,0.f,0.f};

  u32x2 areg[3];
  float bv[8];
  const int am  = t >> 3;         // 0..63 (A row within 64-row pass)
  const int akp = (t & 7) * 2;    // u32-pair within 16-u32 row chunk
  const int bn  = t & 127;        // B: n within tile
  const int bk8 = (t >> 7) * 8;   // B: k-base (0,8,16,24)

  auto load_tile = [&](int it) {
    int kg = k0 + it*32;
#pragma unroll
    for (int i = 0; i < 3; ++i) {
      int m = am + i*64;
      areg[i] = *(const u32x2*)&A[(size_t)m*ldAu + (kg>>1) + akp];
    }
    int gn = n0 + bn;
    bool okn = (gn < N);
#pragma unroll
    for (int i = 0; i < 8; ++i) {
      int rr = kg + bk8 + i;
      size_t srow = PERM ? ((size_t)(rr & 255)*PP + (rr >> 8)) : (size_t)rr;
      bv[i] = okn ? Bm[srow*ldB + gn] : 0.f;
    }
  };

  load_tile(0);
  for (int it = 0; it < myc; ++it) {
    __syncthreads();
#pragma unroll
    for (int i = 0; i < 3; ++i) {
      int m = am + i*64;
      *(u32x2*)&lds_a[m*20 + akp] = areg[i];
    }
    {
      u32x2 w01 = { pk2(bv[0], bv[1]), pk2(bv[2], bv[3]) };
      u32x2 w23 = { pk2(bv[4], bv[5]), pk2(bv[6], bv[7]) };
      *(u32x2*)&lds_b[bn*18 + (bk8>>1)]     = w01;
      *(u32x2*)&lds_b[bn*18 + (bk8>>1) + 2] = w23;
    }
    __syncthreads();
    if (it + 1 < myc) load_tile(it + 1);      // overlap HBM with compute

    bf16x8 af[3];
#pragma unroll
    for (int mf = 0; mf < 3; ++mf) {
      u32x4 ra = *(const u32x4*)&lds_a[(m0w + mf*16 + lrow)*20 + lg*4];
      af[mf] = __builtin_bit_cast(bf16x8, ra);
    }
    bf16x8 bfrag[4];
#pragma unroll
    for (int nf = 0; nf < 4; ++nf) {
      int col = n0w + nf*16 + lrow;
      u32x2 r0 = *(const u32x2*)&lds_b[col*18 + lg*4];
      u32x2 r1 = *(const u32x2*)&lds_b[col*18 + lg*4 + 2];
      u32x4 ub = { r0[0], r0[1], r1[0], r1[1] };
      bfrag[nf] = __builtin_bit_cast(bf16x8, ub);
    }
#pragma unroll
    for (int nf = 0; nf < 4; ++nf)
#pragma unroll
      for (int mf = 0; mf < 3; ++mf)
        acc[mf][nf] = __builtin_amdgcn_mfma_f32_16x16x32_bf16(af[mf], bfrag[nf], acc[mf][nf], 0, 0, 0);
  }

#pragma unroll
  for (int mf = 0; mf < 3; ++mf) {
#pragma unroll
    for (int nf = 0; nf < 4; ++nf) {
      int gcol = n0 + n0w + nf*16 + lrow;
      if (gcol < N) {
#pragma unroll
        for (int rr = 0; rr < 4; ++rr) {
          int m = m0w + mf*16 + lg*4 + rr;
          partial[((size_t)s*NROIS + m)*N + gcol] = f2bf(acc[mf][nf][rr]);
        }
      }
    }
  }
}

// ------- reduce bf16 partials + bias + relu -> bf16 f (4 vals/thread) ---------
__global__ __launch_bounds__(256) void reduce_kernel(
    const unsigned short* __restrict__ partial, const float* __restrict__ bias,
    unsigned short* __restrict__ outp, int N, int S)
{
  int nn = (blockIdx.x*256 + threadIdx.x) * 4;
  int m  = blockIdx.y;
  if (nn >= N) return;
  f32x4 a = *(const f32x4*)&bias[nn];
  size_t stride = (size_t)NROIS * N;
  const unsigned short* p = &partial[(size_t)m*N + nn];
#pragma unroll 4
  for (int s = 0; s < S; ++s) {
    u32x2 v = *(const u32x2*)&p[(size_t)s*stride];
    a[0] += bf_lo(v[0]); a[1] += bf_hi(v[0]);
    a[2] += bf_lo(v[1]); a[3] += bf_hi(v[1]);
  }
  a[0] = fmaxf(a[0], 0.f); a[1] = fmaxf(a[1], 0.f);
  a[2] = fmaxf(a[2], 0.f); a[3] = fmaxf(a[3], 0.f);
  u32x2 pkd = { pk2(a[0], a[1]), pk2(a[2], a[3]) };
  *(u32x2*)&outp[(size_t)m*N + nn] = pkd;
}

// ------- reduce3: om[n][d] = b3[d] + sum_s p3[s][n][d]  (f32 out, 588 wide) ---
__global__ __launch_bounds__(640) void reduce3_kernel(
    const unsigned short* __restrict__ p3, const float* __restrict__ b3,
    float* __restrict__ om, int S)
{
  int d = threadIdx.x;
  int nn = blockIdx.x;
  if (d >= 3*PP) return;
  float a = b3[d];
#pragma unroll 4
  for (int s = 0; s < S; ++s)
    a += bf_u16(p3[((size_t)s*NROIS + nn)*(3*PP) + d]);
  om[(size_t)nn*(3*PP) + d] = a;
}

extern "C" void kernel_launch(void* const* d_in, const int* in_sizes, int n_in,
                              void* d_out, int out_size, void* d_ws, size_t ws_size,
                              hipStream_t stream)
{
  const float* x    = (const float*)d_in[0];
  const float* rois = (const float*)d_in[1];
  const float* w1   = (const float*)d_in[2];
  const float* b1   = (const float*)d_in[3];
  const float* w2   = (const float*)d_in[4];
  const float* b2   = (const float*)d_in[5];
  const float* w3   = (const float*)d_in[6];
  const float* b3   = (const float*)d_in[7];

  char* ws = (char*)d_ws;
  size_t off = 0;
  unsigned* xt = (unsigned*)(ws + off);               off += (size_t)2*(HH*WW)*(CCH/2)*4;
  unsigned short* base = (unsigned short*)(ws + off); off += (size_t)NROIS*KDIM*2;
  unsigned short* f1 = (unsigned short*)(ws + off);   off += (size_t)NROIS*FCDIM*2;
  unsigned short* f2 = (unsigned short*)(ws + off);   off += (size_t)NROIS*FCDIM*2;
  float* om = (float*)(ws + off);                     off += (size_t)NROIS*(3*PP)*4;
  const int S1 = 64, S2 = 32, S3 = 16;
  unsigned short* partial1 = (unsigned short*)(ws + off); off += (size_t)S1*NROIS*FCDIM*2;  // 25.2MB
  unsigned short* partial2 = (unsigned short*)(ws + off); off += (size_t)S2*NROIS*FCDIM*2;  // 12.6MB
  unsigned short* partial3 = (unsigned short*)(ws + off); off += (size_t)S3*NROIS*(3*PP)*2; // 3.6MB
  (void)ws_size;

  // 1) transpose+bf16 x -> xt
  transpose_x_kernel<<<dim3(512, 8, 2), dim3(32, 8), 0, stream>>>(x, xt);
  // 2) base pool -> bf16 [192, 50176] (k = p*256+c)
  pool_kernel<0><<<dim3(NROIS, PP/4), 256, 0, stream>>>(xt, rois, nullptr, base);
  // 3) f1 = relu(base @ w1 + b1); 1568 K-chunks, 64 splits, XCD-swizzled
  gemm_splitk<1,1><<<8*S1, 512, 0, stream>>>((const unsigned*)base, KDIM/2, w1, FCDIM, FCDIM, partial1, 8, S1, KDIM/32);
  reduce_kernel<<<dim3(1, NROIS), 256, 0, stream>>>(partial1, b1, f1, FCDIM, S1);
  // 4) f2 = relu(f1 @ w2 + b2)
  gemm_splitk<0,1><<<8*S2, 512, 0, stream>>>((const unsigned*)f1, FCDIM/2, w2, FCDIM, FCDIM, partial2, 8, S2, FCDIM/32);
  reduce_kernel<<<dim3(1, NROIS), 256, 0, stream>>>(partial2, b2, f2, FCDIM, S2);
  // 5) partial3 = split-K of f2 @ w3 (N = 588)
  gemm_splitk<0,0><<<5*S3, 512, 0, stream>>>((const unsigned*)f2, FCDIM/2, w3, 3*PP, 3*PP, partial3, 5, S3, FCDIM/32);
  // 5b) om = b3 + sum partial3 (f32)  — un-fused from pool1 (48 serial
  // broadcast loads were prepended to every pool1 block's critical path)
  reduce3_kernel<<<NROIS, 640, 0, stream>>>(partial3, b3, om, S3);
  // 6) final pool reads om, * sigmoid(mask) -> d_out
  pool_kernel<1><<<dim3(NROIS, PP/4), 256, 0, stream>>>(xt, rois, om, d_out);
}